// Round 1
// baseline (476.761 us; speedup 1.0000x reference)
//
#include <hip/hip_runtime.h>
#include <math.h>

// QuantumNeuralNetwork: 12-qubit, 16-layer RY+CNOT-ring state-vector sim.
// Design round 1: one wave (64 threads) per batch state; full 4096-amp state
// in registers (64 complex amps per thread). RY gates are real 2x2 rotations:
//   qubits 0..3,10,11 -> register-local pair mixes (amp bits 11..8, 1, 0)
//   qubits 4..9       -> lane-xor shuffles     (amp bits 7..2 = lane bits 5..0)
// CNOT ring composes to one GF(2)-linear permutation G, applied once per layer
// via a 16 KB LDS gather (re/im split so occupancy stays 10 blocks/CU).
// Swizzle s(x)=x^(x>>6) makes write+gather phases 2-way bank aliasing (free).

#define NQ      12
#define DIM     4096
#define NLAYERS 16
#define BATCH   2048
#define NCLASS  5

// Composite CNOT-ring gather map: psi_new[i] = psi_old[gperm(i)].
// Mirrors reference composition: psi = psi[:,p_0][:,p_1]...[:,p_11]
// => G = p_0 o p_1 o ... o p_11 (innermost p_11 applied to i first).
__host__ __device__ constexpr unsigned gperm(unsigned i) {
  for (int q = 11; q >= 0; --q) {
    const unsigned cbit = 1u << (11 - q);
    const unsigned tbit = 1u << (11 - ((q + 1) % 12));
    if (i & cbit) i ^= tbit;
  }
  return i;
}
// LDS slot swizzle (linear over GF(2)) -> conflict-free phases.
__host__ __device__ constexpr unsigned swz(unsigned x) { return x ^ (x >> 6); }
// r (=hi*4+lo) -> amp bits owned by the register index (bits 8..11 and 0..1)
__host__ __device__ constexpr unsigned ar_of(int r) {
  return (unsigned)(((r >> 2) << 8) | (r & 3));
}

__global__ __launch_bounds__(64, 2)
void qnn_sim(const float* __restrict__ zr, const float* __restrict__ zi,
             const float* __restrict__ thetas, float* __restrict__ out) {
  __shared__ float buf[DIM];  // 16 KB: one component of one state
  const int b = blockIdx.x;
  const int lane = threadIdx.x;                 // 0..63
  const unsigned Ab  = (unsigned)lane << 2;     // lane's amp-bit contribution
  const unsigned sAb = swz(Ab);                 // own-slot base
  const unsigned sGb = swz(gperm(Ab));          // gather-slot base (G linear)

  float re[64], im[64];
  const float* zrb = zr + (size_t)b * DIM;
  const float* zib = zi + (size_t)b * DIM;
#pragma unroll
  for (int hi = 0; hi < 16; ++hi) {
    const float4 v = *(const float4*)(zrb + ((hi << 8) | Ab));
    const float4 u = *(const float4*)(zib + ((hi << 8) | Ab));
    re[4*hi+0] = v.x; re[4*hi+1] = v.y; re[4*hi+2] = v.z; re[4*hi+3] = v.w;
    im[4*hi+0] = u.x; im[4*hi+1] = u.y; im[4*hi+2] = u.z; im[4*hi+3] = u.w;
  }

#pragma unroll 1
  for (int l = 0; l < NLAYERS; ++l) {
    const float* th = thetas + l * NQ;

    // ---- register-local gates: qubit q -> r-mask ----
    // q0->bit11->r32, q1->bit10->r16, q2->bit9->r8, q3->bit8->r4,
    // q10->bit1->r2, q11->bit0->r1
    {
      const int qlist[6] = {0, 1, 2, 3, 10, 11};
      const int mlist[6] = {32, 16, 8, 4, 2, 1};
#pragma unroll
      for (int g = 0; g < 6; ++g) {
        const float a = 0.5f * th[qlist[g]];
        const float c = __cosf(a), s = __sinf(a);
        const int m = mlist[g];
#pragma unroll
        for (int r = 0; r < 64; ++r) {
          if (r & m) continue;
          const int r1 = r | m;
          const float a0 = re[r], a1 = re[r1];
          re[r]  = c * a0 - s * a1;
          re[r1] = s * a0 + c * a1;
          const float b0 = im[r], b1 = im[r1];
          im[r]  = c * b0 - s * b1;
          im[r1] = s * b0 + c * b1;
        }
      }
    }

    // ---- cross-lane gates: qubits 4..9, lane-xor mask 1<<(9-q) ----
#pragma unroll 1
    for (int q = 4; q <= 9; ++q) {
      const float a = 0.5f * th[q];
      const float c = __cosf(a), s = __sinf(a);
      const int lb = 9 - q;
      const int lm = 1 << lb;
      // side = amp bit (11-q) = lane bit lb; new = c*me + (side ? +s : -s)*partner
      const float ss = ((lane >> lb) & 1) ? s : -s;
#pragma unroll
      for (int r = 0; r < 64; ++r) {
        const float pr = __shfl_xor(re[r], lm);
        const float pq = __shfl_xor(im[r], lm);
        re[r] = __builtin_fmaf(c, re[r], ss * pr);
        im[r] = __builtin_fmaf(c, im[r], ss * pq);
      }
    }

    // ---- CNOT-ring permutation via LDS gather (per component) ----
    __syncthreads();  // protect previous layer's reads
#pragma unroll
    for (int r = 0; r < 64; ++r) buf[sAb ^ swz(ar_of(r))] = re[r];
    __syncthreads();
#pragma unroll
    for (int r = 0; r < 64; ++r) re[r] = buf[sGb ^ swz(gperm(ar_of(r)))];
    __syncthreads();
#pragma unroll
    for (int r = 0; r < 64; ++r) buf[sAb ^ swz(ar_of(r))] = im[r];
    __syncthreads();
#pragma unroll
    for (int r = 0; r < 64; ++r) im[r] = buf[sGb ^ swz(gperm(ar_of(r)))];
    // next layer's first LDS write is guarded by its leading __syncthreads()
  }

  // ---- Z expectations: sign(wire w) = 1-2*bit(11-w)(amp) ----
  // wires 0..3 -> r bits 5..2 (constexpr per r); wire 4 -> lane bit 5
  float S = 0.f, S0 = 0.f, S1 = 0.f, S2 = 0.f, S3 = 0.f;
#pragma unroll
  for (int r = 0; r < 64; ++r) {
    const float p = re[r] * re[r] + im[r] * im[r];
    S  += p;
    S0 += (r & 32) ? -p : p;
    S1 += (r & 16) ? -p : p;
    S2 += (r & 8)  ? -p : p;
    S3 += (r & 4)  ? -p : p;
  }
  float e0 = S0, e1 = S1, e2 = S2, e3 = S3;
  float e4 = (lane & 32) ? -S : S;
#pragma unroll
  for (int off = 32; off >= 1; off >>= 1) {
    e0 += __shfl_xor(e0, off);
    e1 += __shfl_xor(e1, off);
    e2 += __shfl_xor(e2, off);
    e3 += __shfl_xor(e3, off);
    e4 += __shfl_xor(e4, off);
  }
  if (lane == 0) {
    float* o = out + 1 + (size_t)b * NCLASS;
    o[0] = e0; o[1] = e1; o[2] = e2; o[3] = e3; o[4] = e4;
  }
}

// loss = mean_b( logsumexp(o_b) - o_b[y_b] ); outputs live at out[1..]
__global__ __launch_bounds__(1024)
void qnn_loss(const float* __restrict__ outv, const int* __restrict__ y,
              float* __restrict__ loss_out) {
  __shared__ float red[16];
  const int t = threadIdx.x;
  float acc = 0.f;
  for (int s = t; s < BATCH; s += 1024) {
    const float* o = outv + 1 + (size_t)s * NCLASS;
    const float o0 = o[0], o1 = o[1], o2 = o[2], o3 = o[3], o4 = o[4];
    float m = fmaxf(fmaxf(fmaxf(o0, o1), fmaxf(o2, o3)), o4);
    const float sum = expf(o0 - m) + expf(o1 - m) + expf(o2 - m) +
                      expf(o3 - m) + expf(o4 - m);
    const float lse = m + logf(sum);
    acc += lse - o[y[s]];
  }
#pragma unroll
  for (int off = 32; off >= 1; off >>= 1) acc += __shfl_xor(acc, off);
  if ((t & 63) == 0) red[t >> 6] = acc;
  __syncthreads();
  if (t == 0) {
    float tot = 0.f;
#pragma unroll
    for (int i = 0; i < 16; ++i) tot += red[i];
    loss_out[0] = tot * (1.0f / BATCH);
  }
}

extern "C" void kernel_launch(void* const* d_in, const int* in_sizes, int n_in,
                              void* d_out, int out_size, void* d_ws, size_t ws_size,
                              hipStream_t stream) {
  const float* zr = (const float*)d_in[0];
  const float* zi = (const float*)d_in[1];
  const float* th = (const float*)d_in[2];
  const int*   y  = (const int*)d_in[3];
  float* out = (float*)d_out;
  qnn_sim<<<BATCH, 64, 0, stream>>>(zr, zi, th, out);
  qnn_loss<<<1, 1024, 0, stream>>>(out, y, out);
}

// Round 2
// 303.182 us; speedup vs baseline: 1.5725x; 1.5725x over previous
//
#include <hip/hip_runtime.h>
#include <math.h>

// QuantumNeuralNetwork: 12-qubit, 16-layer RY+CNOT-ring state-vector sim.
// Round 2: one state per 128-thread block (2 waves), 32 complex amps/lane
// (64 VGPRs state) -- fixes round-1 scratch spilling (498 MB FETCH).
// Layer structure (all RY gates commute):
//   L1 layout: lane t owns amp bits 11..5, reg r1 = amp bits 4..0
//     -> q7..q11 register-local; q5,q6 via quad-perm DPP (amp bits 6,5 = t1,t0)
//   LDS trip 1 -> L2 layout: reg r2 = amp bits 11..7, lane owns bits 6..0
//     -> q0..q4 register-local
//   LDS trip 2 -> back to L1 FUSED with the CNOT-ring permutation G (linear).
// Swizzle f(x)=x^(x>>6): all 4 LDS phases have rank-5 bank projection -> 2-way
// aliasing only (free, m136).

#define DIM     4096
#define NLAYERS 16
#define BATCH   2048
#define NCLASS  5

// Composite CNOT-ring gather: psi_new[i] = psi_old[gperm(i)]. GF(2)-linear.
// (verified correct in round 1; equals i ^ (i>>1) ^ ((i&1)?0xC00:0))
__host__ __device__ constexpr unsigned gperm(unsigned i) {
  for (int q = 11; q >= 0; --q) {
    const unsigned cbit = 1u << (11 - q);
    const unsigned tbit = 1u << (11 - ((q + 1) % 12));
    if (i & cbit) i ^= tbit;
  }
  return i;
}
__host__ __device__ constexpr unsigned swz(unsigned x) { return x ^ (x >> 6); }

// quad_perm DPP permute (VALU, no LDS): CTRL 0x4E = xor-2, 0xB1 = xor-1
template<int CTRL>
__device__ __forceinline__ float dppf(float x) {
  return __int_as_float(__builtin_amdgcn_update_dpp(
      0, __float_as_int(x), CTRL, 0xF, 0xF, true));
}

__global__ __launch_bounds__(128, 4)
void qnn_sim(const float* __restrict__ zr, const float* __restrict__ zi,
             const float* __restrict__ thetas, float* __restrict__ out) {
  __shared__ float buf[DIM];  // 16 KB: one component of the state
  const int b = blockIdx.x;
  const int t = threadIdx.x;  // 0..127

  // Layer-invariant LDS slot bases (float indices), f(x)=x^(x>>6):
  // W1 : slot = f((t<<5)|r1)          = wb1 ^ r1
  // R1/W2: slot = f((r2<<7)|t)        = rb1 ^ ((r2<<7)|(r2<<1))
  // R2 : slot = f(G((t<<5)|r1))       = rb2 ^ swz(gperm(r1))   [G,f linear]
  const int wb1 = ((t << 5) ^ (t >> 1));
  const int rb1 = (t ^ (t >> 6));
  const int Xt  = ((t << 5) ^ (t << 4)) & 0xFFF;  // G(t<<5)
  const int rb2 = (Xt ^ (Xt >> 6));

  float re[32], im[32];
  {
    const float* zrb = zr + (size_t)b * DIM + (t << 5);
    const float* zib = zi + (size_t)b * DIM + (t << 5);
#pragma unroll
    for (int k = 0; k < 8; ++k) {
      const float4 v = ((const float4*)zrb)[k];
      const float4 u = ((const float4*)zib)[k];
      re[4*k+0]=v.x; re[4*k+1]=v.y; re[4*k+2]=v.z; re[4*k+3]=v.w;
      im[4*k+0]=u.x; im[4*k+1]=u.y; im[4*k+2]=u.z; im[4*k+3]=u.w;
    }
  }

#pragma unroll 1
  for (int l = 0; l < NLAYERS; ++l) {
    const float* th = thetas + l * 12;

    // ---- L1 register gates: q7..q11  (pair masks r1: 16,8,4,2,1) ----
#pragma unroll
    for (int g = 0; g < 5; ++g) {
      const float a = 0.5f * th[7 + g];
      const float c = __cosf(a), s = __sinf(a);
      const int m = 16 >> g;
#pragma unroll
      for (int r = 0; r < 32; ++r) {
        if (r & m) continue;
        const int rp = r | m;
        const float a0 = re[r], a1 = re[rp];
        re[r]  = c * a0 - s * a1;
        re[rp] = s * a0 + c * a1;
        const float b0 = im[r], b1 = im[rp];
        im[r]  = c * b0 - s * b1;
        im[rp] = s * b0 + c * b1;
      }
    }

    // ---- DPP gates: q5 (amp bit6 = t1, xor-2) ; q6 (amp bit5 = t0, xor-1)
    // elem with bit=1 gets +s*partner, bit=0 gets -s*partner
    {
      const float a5 = 0.5f * th[5];
      const float c5 = __cosf(a5), s5 = __sinf(a5);
      const float ss5 = (t & 2) ? s5 : -s5;
#pragma unroll
      for (int r = 0; r < 32; ++r) {
        re[r] = __builtin_fmaf(c5, re[r], ss5 * dppf<0x4E>(re[r]));
        im[r] = __builtin_fmaf(c5, im[r], ss5 * dppf<0x4E>(im[r]));
      }
      const float a6 = 0.5f * th[6];
      const float c6 = __cosf(a6), s6 = __sinf(a6);
      const float ss6 = (t & 1) ? s6 : -s6;
#pragma unroll
      for (int r = 0; r < 32; ++r) {
        re[r] = __builtin_fmaf(c6, re[r], ss6 * dppf<0xB1>(re[r]));
        im[r] = __builtin_fmaf(c6, im[r], ss6 * dppf<0xB1>(im[r]));
      }
    }

    // ---- trip 1: L1 -> L2 (per component) ----
    __syncthreads();  // prev layer's reads / prev phase done
#pragma unroll
    for (int r = 0; r < 32; ++r) buf[wb1 ^ r] = re[r];
    __syncthreads();
#pragma unroll
    for (int r = 0; r < 32; ++r) re[r] = buf[rb1 ^ ((r << 7) | (r << 1))];
    __syncthreads();
#pragma unroll
    for (int r = 0; r < 32; ++r) buf[wb1 ^ r] = im[r];
    __syncthreads();
#pragma unroll
    for (int r = 0; r < 32; ++r) im[r] = buf[rb1 ^ ((r << 7) | (r << 1))];

    // ---- L2 register gates: q0..q4 (pair masks r2: 16,8,4,2,1) ----
#pragma unroll
    for (int g = 0; g < 5; ++g) {
      const float a = 0.5f * th[g];
      const float c = __cosf(a), s = __sinf(a);
      const int m = 16 >> g;
#pragma unroll
      for (int r = 0; r < 32; ++r) {
        if (r & m) continue;
        const int rp = r | m;
        const float a0 = re[r], a1 = re[rp];
        re[r]  = c * a0 - s * a1;
        re[rp] = s * a0 + c * a1;
        const float b0 = im[r], b1 = im[rp];
        im[r]  = c * b0 - s * b1;
        im[rp] = s * b0 + c * b1;
      }
    }

    // ---- trip 2: L2 -> L1 fused with CNOT-ring gather ----
    __syncthreads();
#pragma unroll
    for (int r = 0; r < 32; ++r) buf[rb1 ^ ((r << 7) | (r << 1))] = re[r];
    __syncthreads();
#pragma unroll
    for (int r = 0; r < 32; ++r) re[r] = buf[rb2 ^ (int)swz(gperm((unsigned)r))];
    __syncthreads();
#pragma unroll
    for (int r = 0; r < 32; ++r) buf[rb1 ^ ((r << 7) | (r << 1))] = im[r];
    __syncthreads();
#pragma unroll
    for (int r = 0; r < 32; ++r) im[r] = buf[rb2 ^ (int)swz(gperm((unsigned)r))];
  }

  // ---- Z expectations: wire w sign = amp bit (11-w) = t bit (6-w) ----
  float P = 0.f;
#pragma unroll
  for (int r = 0; r < 32; ++r) P += re[r] * re[r] + im[r] * im[r];
  float e[5];
#pragma unroll
  for (int w = 0; w < 5; ++w) e[w] = ((t >> (6 - w)) & 1) ? -P : P;
#pragma unroll
  for (int off = 32; off >= 1; off >>= 1) {
#pragma unroll
    for (int w = 0; w < 5; ++w) e[w] += __shfl_xor(e[w], off);
  }
  __syncthreads();  // protect buf (last R2-im reads done)
  if ((t & 63) == 0) {
#pragma unroll
    for (int w = 0; w < 5; ++w) buf[(t >> 6) * 8 + w] = e[w];
  }
  __syncthreads();
  if (t == 0) {
    float* o = out + 1 + (size_t)b * NCLASS;
#pragma unroll
    for (int w = 0; w < 5; ++w) o[w] = buf[w] + buf[8 + w];
  }
}

// loss = mean_b( logsumexp(o_b) - o_b[y_b] ); outputs live at out[1..]
__global__ __launch_bounds__(1024)
void qnn_loss(const float* __restrict__ outv, const int* __restrict__ y,
              float* __restrict__ loss_out) {
  __shared__ float red[16];
  const int t = threadIdx.x;
  float acc = 0.f;
  for (int s = t; s < BATCH; s += 1024) {
    const float* o = outv + 1 + (size_t)s * NCLASS;
    const float o0 = o[0], o1 = o[1], o2 = o[2], o3 = o[3], o4 = o[4];
    float m = fmaxf(fmaxf(fmaxf(o0, o1), fmaxf(o2, o3)), o4);
    const float sum = expf(o0 - m) + expf(o1 - m) + expf(o2 - m) +
                      expf(o3 - m) + expf(o4 - m);
    const float lse = m + logf(sum);
    acc += lse - o[y[s]];
  }
#pragma unroll
  for (int off = 32; off >= 1; off >>= 1) acc += __shfl_xor(acc, off);
  if ((t & 63) == 0) red[t >> 6] = acc;
  __syncthreads();
  if (t == 0) {
    float tot = 0.f;
#pragma unroll
    for (int i = 0; i < 16; ++i) tot += red[i];
    loss_out[0] = tot * (1.0f / BATCH);
  }
}

extern "C" void kernel_launch(void* const* d_in, const int* in_sizes, int n_in,
                              void* d_out, int out_size, void* d_ws, size_t ws_size,
                              hipStream_t stream) {
  const float* zr = (const float*)d_in[0];
  const float* zi = (const float*)d_in[1];
  const float* th = (const float*)d_in[2];
  const int*   y  = (const int*)d_in[3];
  float* out = (float*)d_out;
  qnn_sim<<<BATCH, 128, 0, stream>>>(zr, zi, th, out);
  qnn_loss<<<1, 1024, 0, stream>>>(out, y, out);
}